// Round 1
// baseline (225.124 us; speedup 1.0000x reference)
//
#include <hip/hip_runtime.h>

// FlatTensorRouter: x(4,4096,4096) f32, W(64,4096) f32
// out = [top_k_weights (16384*2) | top_k_indices-as-f32 (16384*2) | aux_loss (1)]
// ws  = [Wt (4096*64 f32) | acc64 (64 f32)]

__global__ __launch_bounds__(256) void prep_kernel(const float* __restrict__ W,
                                                   float* __restrict__ Wt,
                                                   float* __restrict__ acc64) {
  int idx = blockIdx.x * 256 + threadIdx.x;   // 0..262143, coalesced read of W
  int e = idx >> 12;
  int k = idx & 4095;
  Wt[k * 64 + e] = W[idx];
  if (idx < 64) acc64[idx] = 0.0f;
}

__global__ __launch_bounds__(1024, 4) void router_main(const float* __restrict__ x,
                                                       const float* __restrict__ Wt,
                                                       float* __restrict__ out,
                                                       float* __restrict__ acc64) {
  __shared__ float lg[64][65];                // logits tile, padded (2-way = free)
  const int lane = threadIdx.x & 63;
  const int w = threadIdx.x >> 6;             // wave id 0..15, k-chunk owner
  const int token = blockIdx.x * 64 + lane;

  for (int i = threadIdx.x; i < 64 * 65; i += 1024) (&lg[0][0])[i] = 0.0f;
  __syncthreads();

  float acc[64];
#pragma unroll
  for (int e = 0; e < 64; ++e) acc[e] = 0.0f;

  // each lane streams its own token row segment (contiguous per lane)
  const float4* xv4 = (const float4*)(x + (size_t)token * 4096 + w * 256);
  const int kbase = __builtin_amdgcn_readfirstlane(w * 256);  // force SGPR path for W

  float4 xc = xv4[0];
  for (int kt = 0; kt < 64; ++kt) {           // 64 iters x 4 k = 256 k per wave
    float4 xn = xc;
    if (kt < 63) xn = xv4[kt + 1];            // guard: avoid OOB read on last token
    const float4* wr = (const float4*)(Wt + (size_t)(kbase + kt * 4) * 64);
#pragma unroll
    for (int j = 0; j < 4; ++j) {
      const float xj = (j == 0) ? xc.x : (j == 1) ? xc.y : (j == 2) ? xc.z : xc.w;
#pragma unroll
      for (int e4 = 0; e4 < 16; ++e4) {
        const float4 wv = wr[j * 16 + e4];    // wave-uniform -> s_load
        acc[e4 * 4 + 0] = fmaf(xj, wv.x, acc[e4 * 4 + 0]);
        acc[e4 * 4 + 1] = fmaf(xj, wv.y, acc[e4 * 4 + 1]);
        acc[e4 * 4 + 2] = fmaf(xj, wv.z, acc[e4 * 4 + 2]);
        acc[e4 * 4 + 3] = fmaf(xj, wv.w, acc[e4 * 4 + 3]);
      }
    }
    xc = xn;
  }

  // cross-wave K reduction into LDS (ds_add_f32; 64 lanes hit distinct addrs)
#pragma unroll
  for (int e = 0; e < 64; ++e) atomicAdd(&lg[lane][e], acc[e]);
  __syncthreads();

  if (w == 0) {
    // lane t owns token t: full 64 logits available
    float l[64];
    float m1 = -3.4e38f, m2 = -3.4e38f;
    int i1 = 0, i2 = 0;
#pragma unroll
    for (int e = 0; e < 64; ++e) {
      float v = lg[lane][e];
      l[e] = v;
      if (v > m1) { m2 = m1; i2 = i1; m1 = v; i1 = e; }       // strict > = lax.top_k tie-break
      else if (v > m2) { m2 = v; i2 = e; }
    }
    float den = 0.0f;
#pragma unroll
    for (int e = 0; e < 64; ++e) {
      float p = __expf(l[e] - m1);
      l[e] = p;
      den += p;
    }
    float rden = 1.0f / den;
#pragma unroll
    for (int e = 0; e < 64; ++e) lg[lane][e] = l[e] * rden;   // normalized probs back to LDS

    float e21 = __expf(m2 - m1);
    float w1 = 1.0f / (1.0f + e21);           // softmax([m1,m2])
    float w2 = e21 * w1;
    out[2 * token + 0] = w1;
    out[2 * token + 1] = w2;
    out[32768 + 2 * token + 0] = (float)i1;   // indices as float values
    out[32768 + 2 * token + 1] = (float)i2;
  }
  __syncthreads();

  if (w == 1) {
    // lane e: column-sum probs over 64 tokens (conflict-free: (t+e)%32 spread)
    float s = 0.0f;
#pragma unroll
    for (int t = 0; t < 64; ++t) s += lg[t][lane];
    atomicAdd(&acc64[lane], s);               // 64 distinct addrs, 1 instr/block
  }
}

__global__ __launch_bounds__(64) void aux_kernel(const float* __restrict__ acc64,
                                                 float* __restrict__ out) {
  float m = acc64[threadIdx.x] * (1.0f / 16384.0f);
  float v = m * m;
#pragma unroll
  for (int off = 32; off > 0; off >>= 1) v += __shfl_down(v, off);
  if (threadIdx.x == 0) out[65536] = v * 64.0f;
}

extern "C" void kernel_launch(void* const* d_in, const int* in_sizes, int n_in,
                              void* d_out, int out_size, void* d_ws, size_t ws_size,
                              hipStream_t stream) {
  const float* x = (const float*)d_in[0];
  const float* W = (const float*)d_in[1];
  float* out = (float*)d_out;
  float* Wt = (float*)d_ws;
  float* acc64 = (float*)d_ws + 4096 * 64;

  prep_kernel<<<1024, 256, 0, stream>>>(W, Wt, acc64);
  router_main<<<256, 1024, 0, stream>>>(x, Wt, out, acc64);
  aux_kernel<<<1, 64, 0, stream>>>(acc64, out);
}